// Round 4
// baseline (112.614 us; speedup 1.0000x reference)
//
#include <hip/hip_runtime.h>

// Problem constants (B, L, H, D, T) = (8, 4096, 8, 128, 128)
constexpr int B = 8;
constexpr int L = 4096;
constexpr int H = 8;
constexpr int D = 128;
constexpr int T = 128;

constexpr int ROW4 = H * D / 4;            // 256 float4 per (b,p) row
constexpr int NROWS = B * L;               // 32768 rows per tensor
constexpr long long KV_ELEMS = (long long)B * L * H * D;  // floats per tensor

constexpr int ROWS_PER_BLOCK = 16;         // block tile: 16 rows x 4 KiB = 64 KiB
constexpr int NBLOCKS = NROWS / ROWS_PER_BLOCK;  // 2048

// ---------------------------------------------------------------------------
// Fused copy+update. Block-contiguous tiling: block owns 16 consecutive rows;
// one iteration = one row (256 thr x float4 = 4 KiB), so in-flight requests
// stay within a small contiguous window (DRAM page locality) instead of the
// 8 MiB grid-stride jumps that capped R1/R2 at 5.1/3.8 TB/s.
// Cache reads are UNCONDITIONAL (schedulable stream); the rare updated row
// is patched by a wave-uniform, usually-skipped branch before the store.
// ---------------------------------------------------------------------------
__global__ __launch_bounds__(256) void kv_fused(
    const float4* __restrict__ keys,
    const float4* __restrict__ values,
    const int*    __restrict__ lengths,
    const float4* __restrict__ new_keys,
    const float4* __restrict__ new_values,
    const int*    __restrict__ new_lengths,
    float4* __restrict__ out_k,
    float4* __restrict__ out_v,
    float*  __restrict__ out_len)
{
    const int c    = threadIdx.x;          // float4 index within row
    const int row0 = blockIdx.x * ROWS_PER_BLOCK;

    // A 16-row block tile crosses at most one batch boundary; lengths[] loads
    // below are scalar L1 hits, so just read them per iteration.
    #pragma unroll 4
    for (int j = 0; j < ROWS_PER_BLOCK; ++j) {
        const int row = row0 + j;
        const int i   = (row << 8) + c;    // float4 index, max 2^23 -> int ok

        // unconditional streaming reads
        float4 vk = keys[i];
        float4 vv = values[i];

        const int b  = row >> 12;          // / L
        const int p  = row & (L - 1);
        const int l  = lengths[b];
        const int nl = new_lengths[b];

        if (p >= l && p < l + nl) {        // wave-uniform, taken for <=3% rows
            const int nidx = ((b * T + (p - l)) << 8) + c;
            vk = new_keys[nidx];
            vv = new_values[nidx];
        }

        out_k[i] = vk;
        out_v[i] = vv;
    }

    if (blockIdx.x == 0 && threadIdx.x < B) {
        const int bb = threadIdx.x;
        out_len[bb] = (float)(lengths[bb] + new_lengths[bb]);
    }
}

extern "C" void kernel_launch(void* const* d_in, const int* in_sizes, int n_in,
                              void* d_out, int out_size, void* d_ws, size_t ws_size,
                              hipStream_t stream)
{
    const float4* keys       = (const float4*)d_in[0];
    const float4* values     = (const float4*)d_in[1];
    const int*    lengths    = (const int*)   d_in[2];
    const float4* new_keys   = (const float4*)d_in[3];
    const float4* new_values = (const float4*)d_in[4];
    const int*    new_lengths= (const int*)   d_in[5];

    float*  out     = (float*)d_out;
    float4* out_k   = (float4*)out;
    float4* out_v   = (float4*)(out + KV_ELEMS);
    float*  out_len = out + 2 * KV_ELEMS;

    kv_fused<<<NBLOCKS, 256, 0, stream>>>(keys, values, lengths,
                                          new_keys, new_values, new_lengths,
                                          out_k, out_v, out_len);
}

// Round 6
// 99.881 us; speedup vs baseline: 1.1275x; 1.1275x over previous
//
#include <hip/hip_runtime.h>

// Problem constants (B, L, H, D, T) = (8, 4096, 8, 128, 128)
constexpr int B = 8;
constexpr int L = 4096;
constexpr int H = 8;
constexpr int D = 128;
constexpr int T = 128;

constexpr long long KV_ELEMS = (long long)B * L * H * D;  // floats per tensor
constexpr int TOTAL4 = (int)(KV_ELEMS / 4);               // 8,388,608 float4 per tensor

constexpr int NBLOCKS = 2048;
constexpr int NTHREADS = 256;
constexpr int STRIDE = NBLOCKS * NTHREADS;                // 524288 float4 = 8 MiB phase

// native clang vector type — __builtin_nontemporal_* requires this,
// not HIP_vector_type<float,4>
typedef float f4 __attribute__((ext_vector_type(4)));

// ---------------------------------------------------------------------------
// R1 phase-aligned grid-stride structure (best so far: 105.3 us, 5.1 TB/s),
// plus non-temporal bulk loads/stores: inputs are read exactly once and
// outputs never re-read, so bypassing L2/LLC allocation removes the LLC
// fill/evict churn that sits on top of the 537 MB compulsory traffic.
// ---------------------------------------------------------------------------
__global__ __launch_bounds__(256) void kv_fused_nt(
    const f4* __restrict__ keys,
    const f4* __restrict__ values,
    const int* __restrict__ lengths,
    const f4* __restrict__ new_keys,
    const f4* __restrict__ new_values,
    const int* __restrict__ new_lengths,
    f4* __restrict__ out_k,
    f4* __restrict__ out_v,
    float* __restrict__ out_len)
{
    int i = blockIdx.x * NTHREADS + (int)threadIdx.x;

    // TOTAL4 / STRIDE == 16 exactly
    #pragma unroll 1
    for (int it = 0; it < 16; ++it, i += STRIDE) {
        // unconditional non-temporal streaming reads
        f4 vk = __builtin_nontemporal_load(&keys[i]);
        f4 vv = __builtin_nontemporal_load(&values[i]);

        const int row = i >> 8;            // 256 float4 per (b,p) row
        const int b   = row >> 12;         // / L
        const int p   = row & (L - 1);
        const int l   = lengths[b];        // uniform scalar loads, L1-resident
        const int nl  = new_lengths[b];

        if (p >= l && p < l + nl) {        // wave-uniform, <=3% of rows
            const int c    = i & 255;
            const int nidx = ((b * T + (p - l)) << 8) + c;
            vk = new_keys[nidx];
            vv = new_values[nidx];
        }

        __builtin_nontemporal_store(vk, &out_k[i]);
        __builtin_nontemporal_store(vv, &out_v[i]);
    }

    if (blockIdx.x == 0 && threadIdx.x < B) {
        const int bb = threadIdx.x;
        out_len[bb] = (float)(lengths[bb] + new_lengths[bb]);
    }
}

extern "C" void kernel_launch(void* const* d_in, const int* in_sizes, int n_in,
                              void* d_out, int out_size, void* d_ws, size_t ws_size,
                              hipStream_t stream)
{
    const f4* keys       = (const f4*)d_in[0];
    const f4* values     = (const f4*)d_in[1];
    const int* lengths   = (const int*)d_in[2];
    const f4* new_keys   = (const f4*)d_in[3];
    const f4* new_values = (const f4*)d_in[4];
    const int* new_lengths = (const int*)d_in[5];

    float* out   = (float*)d_out;
    f4* out_k    = (f4*)out;
    f4* out_v    = (f4*)(out + KV_ELEMS);
    float* out_len = out + 2 * KV_ELEMS;

    kv_fused_nt<<<NBLOCKS, NTHREADS, 0, stream>>>(keys, values, lengths,
                                                  new_keys, new_values, new_lengths,
                                                  out_k, out_v, out_len);
}

// Round 7
// 96.956 us; speedup vs baseline: 1.1615x; 1.0302x over previous
//
#include <hip/hip_runtime.h>

// Problem constants (B, L, H, D, T) = (8, 4096, 8, 128, 128)
constexpr int B = 8;
constexpr int L = 4096;
constexpr int H = 8;
constexpr int D = 128;
constexpr int T = 128;

constexpr long long KV_ELEMS = (long long)B * L * H * D;  // floats per tensor
constexpr int TOTAL4 = (int)(KV_ELEMS / 4);               // 8,388,608 float4 per tensor

constexpr int NBLOCKS = 2048;
constexpr int NTHREADS = 256;
constexpr int STRIDE = NBLOCKS * NTHREADS;                // 524288 float4 = 8 MiB phase

// native clang vector type — __builtin_nontemporal_* requires this
typedef float f4 __attribute__((ext_vector_type(4)));

// ---------------------------------------------------------------------------
// Temporal phase-split: all waves copy K (16 phase-aligned grid-stride
// iterations, 1 read-stream + 1 write-stream chip-wide), THEN copy V.
// Same-run evidence: 1 stream = 7.0 TB/s (fill), 2 streams = 6.29 (copy
// ubench), 4 streams = 5.37 (R6 fused). Halving concurrent streams should
// recover most of the copy ceiling. Patch is inline (per-location select),
// so no cross-phase ordering is needed. Non-temporal everywhere (R6: +5%).
// ---------------------------------------------------------------------------
__global__ __launch_bounds__(256) void kv_fused_phased(
    const f4* __restrict__ keys,
    const f4* __restrict__ values,
    const int* __restrict__ lengths,
    const f4* __restrict__ new_keys,
    const f4* __restrict__ new_values,
    const int* __restrict__ new_lengths,
    f4* __restrict__ out_k,
    f4* __restrict__ out_v,
    float* __restrict__ out_len)
{
    const int tid = blockIdx.x * NTHREADS + (int)threadIdx.x;

    #pragma unroll 1
    for (int it = 0; it < 32; ++it) {
        const bool is_k = (it < 16);
        const f4* __restrict__ src  = is_k ? keys     : values;
        const f4* __restrict__ nsrc = is_k ? new_keys : new_values;
        f4* __restrict__ dst        = is_k ? out_k    : out_v;

        const int i = (it & 15) * STRIDE + tid;

        f4 v = __builtin_nontemporal_load(&src[i]);

        const int row = i >> 8;            // 256 float4 per (b,p) row
        const int b   = row >> 12;         // / L
        const int p   = row & (L - 1);
        const int l   = lengths[b];        // uniform scalar loads, L1-resident
        const int nl  = new_lengths[b];

        if (p >= l && p < l + nl) {        // wave-uniform, <=3% of rows
            const int c    = i & 255;
            const int nidx = ((b * T + (p - l)) << 8) + c;
            v = nsrc[nidx];
        }

        __builtin_nontemporal_store(v, &dst[i]);
    }

    if (blockIdx.x == 0 && threadIdx.x < B) {
        const int bb = threadIdx.x;
        out_len[bb] = (float)(lengths[bb] + new_lengths[bb]);
    }
}

extern "C" void kernel_launch(void* const* d_in, const int* in_sizes, int n_in,
                              void* d_out, int out_size, void* d_ws, size_t ws_size,
                              hipStream_t stream)
{
    const f4* keys        = (const f4*)d_in[0];
    const f4* values      = (const f4*)d_in[1];
    const int* lengths    = (const int*)d_in[2];
    const f4* new_keys    = (const f4*)d_in[3];
    const f4* new_values  = (const f4*)d_in[4];
    const int* new_lengths= (const int*)d_in[5];

    float* out     = (float*)d_out;
    f4* out_k      = (f4*)out;
    f4* out_v      = (f4*)(out + KV_ELEMS);
    float* out_len = out + 2 * KV_ELEMS;

    kv_fused_phased<<<NBLOCKS, NTHREADS, 0, stream>>>(keys, values, lengths,
                                                      new_keys, new_values, new_lengths,
                                                      out_k, out_v, out_len);
}